// Round 1
// baseline (472.855 us; speedup 1.0000x reference)
//
#include <hip/hip_runtime.h>

#define B_ 8
#define L_ 512
#define D_ 1024
#define N_ 8192
#define GD_ 64
#define K_ 256

// ---------------- Kernel 1: transpose W (64,1024) -> Wt (1024,64) ----------------
__global__ __launch_bounds__(256) void wt_kernel(const float* __restrict__ W,
                                                 float* __restrict__ Wt) {
  int idx = blockIdx.x * 256 + threadIdx.x;  // 65536 elems
  int d = idx >> 6, g = idx & 63;
  Wt[idx] = W[(size_t)g * D_ + d];
}

// ---------------- Kernel 2: g = x @ W^T, gn = ||g||, gu = g/max(gn,1e-12) --------
// block: 16 tokens x 64 dims; 256 threads: dg = tid&15 (4 dims each), tg = tid>>4 (token)
__global__ __launch_bounds__(256) void gproj_kernel(const float* __restrict__ x,
                                                    const float* __restrict__ Wt,
                                                    float* __restrict__ gu,
                                                    float* __restrict__ gn) {
  const int KC = 128;
  __shared__ float xs[16][KC];        // 8 KB
  __shared__ float wsT[GD_][KC + 4];  // padded: 33.8 KB
  int blk = blockIdx.x;               // 256 blocks
  int b = blk >> 5;
  int t0 = (blk & 31) * 16;
  int tid = threadIdx.x;
  int dg = tid & 15, tg = tid >> 4;
  const float* xb = x + ((size_t)b * L_ + t0) * D_;
  float ax[4] = {0, 0, 0, 0}, ay[4] = {0, 0, 0, 0};
  float az[4] = {0, 0, 0, 0}, aw[4] = {0, 0, 0, 0};
  for (int kc = 0; kc < D_; kc += KC) {
    for (int f = tid; f < 16 * KC / 4; f += 256) {
      int t = f >> 5, k4 = f & 31;
      *(float4*)&xs[t][k4 * 4] = *(const float4*)(xb + (size_t)t * D_ + kc + k4 * 4);
    }
    for (int f = tid; f < GD_ * KC; f += 256) {
      int kk = f >> 6, d = f & 63;
      wsT[d][kk] = Wt[(size_t)(kc + kk) * GD_ + d];
    }
    __syncthreads();
#pragma unroll 4
    for (int kk = 0; kk < KC; kk += 4) {
      float4 xv = *(const float4*)&xs[tg][kk];
#pragma unroll
      for (int dd = 0; dd < 4; ++dd) {
        float4 wv = *(const float4*)&wsT[dg * 4 + dd][kk];
        ax[dd] += xv.x * wv.x;
        ay[dd] += xv.y * wv.y;
        az[dd] += xv.z * wv.z;
        aw[dd] += xv.w * wv.w;
      }
    }
    __syncthreads();
  }
  float g[4];
  double ss = 0.0;
#pragma unroll
  for (int dd = 0; dd < 4; ++dd) {
    g[dd] = (ax[dd] + ay[dd]) + (az[dd] + aw[dd]);
    ss += (double)g[dd] * (double)g[dd];
  }
  // reduce squares across the 16-lane dim-group (within one wave)
#pragma unroll
  for (int off = 1; off < 16; off <<= 1) ss += __shfl_xor(ss, off);
  float gnv = (float)sqrt(ss);
  float dn = fmaxf(gnv, 1e-12f);
  int t = t0 + tg;
  if (dg == 0) gn[(size_t)b * L_ + t] = gnv;
  float* gup = gu + ((size_t)b * L_ + t) * GD_ + dg * 4;
#pragma unroll
  for (int dd = 0; dd < 4; ++dd) gup[dd] = g[dd] / dn;
}

// ---------------- Kernel 3: full 512x512 cosine-sim matrix per batch -------------
__global__ __launch_bounds__(256) void sim_kernel(const float* __restrict__ gu,
                                                  float* __restrict__ simo) {
  __shared__ float A[32][65];
  __shared__ float Bs[32][65];
  int b = blockIdx.z;
  int i0 = blockIdx.y * 32, j0 = blockIdx.x * 32;
  const float* gb = gu + (size_t)b * L_ * GD_;
  int tid = threadIdx.x;
  for (int f = tid; f < 32 * GD_; f += 256) {
    int r = f >> 6, k = f & 63;
    A[r][k] = gb[(size_t)(i0 + r) * GD_ + k];
    Bs[r][k] = gb[(size_t)(j0 + r) * GD_ + k];
  }
  __syncthreads();
  float* sb = simo + (size_t)b * L_ * L_;
  for (int o = tid; o < 1024; o += 256) {
    int r = o >> 5, c = o & 31;
    double acc = 0.0;
#pragma unroll 8
    for (int k = 0; k < GD_; ++k) acc += (double)A[r][k] * (double)Bs[c][k];
    sb[(size_t)(i0 + r) * L_ + (j0 + c)] = (float)acc;
  }
}

// ---------------- Kernel 4: greedy matching via locally-dominant (mutual-best) ---
// one block per batch, 1024 threads = 16 waves; wave-per-token best scans.
// key = (ord(sim) << 18) | (0x3FFFF - (i*512+j))  -> max == (sim desc, i asc, j asc)
__global__ __launch_bounds__(1024) void match_kernel(const float* __restrict__ sim,
                                                     int* __restrict__ keepI,
                                                     int* __restrict__ keepJ) {
  int b = blockIdx.x;
  const float* S = sim + (size_t)b * L_ * L_;
  __shared__ unsigned long long bestkey[L_];
  __shared__ int partner[L_];
  __shared__ short liveList[L_];
  __shared__ short liveTmp[L_];
  __shared__ unsigned char liveF[L_];
  __shared__ unsigned char needs[L_];
  __shared__ int nLiveS, nLiveNew;
  int tid = threadIdx.x;
  int wave = tid >> 6, lane = tid & 63;
  if (tid < L_) {
    partner[tid] = -1;
    liveF[tid] = 1;
    needs[tid] = 1;
    liveList[tid] = (short)tid;
    bestkey[tid] = 0ull;
  }
  if (tid == 0) nLiveS = L_;
  __syncthreads();
  for (int round = 0; round < 300; ++round) {
    int nLive = nLiveS;
    if (nLive == 0) break;
    // phase 1: (re)compute best live partner for tokens whose best died
    for (int idx = wave; idx < nLive; idx += 16) {
      int a = liveList[idx];  // wave-uniform
      if (needs[a]) {
        unsigned long long mk = 0ull;
        for (int k = lane; k < nLive; k += 64) {
          int bb = liveList[k];
          if (bb != a) {
            float sv = S[(size_t)a * L_ + bb];
            unsigned u = __float_as_uint(sv);
            u = (u & 0x80000000u) ? ~u : (u | 0x80000000u);
            int i = a < bb ? a : bb;
            int j = a < bb ? bb : a;
            unsigned long long key =
                ((unsigned long long)u << 18) |
                (unsigned long long)(0x3FFFFu - (((unsigned)i << 9) | (unsigned)j));
            if (key > mk) mk = key;
          }
        }
#pragma unroll
        for (int off = 32; off; off >>= 1) {
          unsigned long long o = __shfl_xor(mk, off);
          if (o > mk) mk = o;
        }
        if (lane == 0) {
          bestkey[a] = mk;
          needs[a] = 0;
        }
      }
    }
    __syncthreads();
    // phase 2: mutual-best pairs match (each endpoint marks itself)
    for (int idx = tid; idx < nLive; idx += 1024) {
      int a = liveList[idx];
      unsigned pk = 0x3FFFFu - (unsigned)(bestkey[a] & 0x3FFFFull);
      int p = ((int)(pk >> 9) == a) ? (int)(pk & 511u) : (int)(pk >> 9);
      unsigned pk2 = 0x3FFFFu - (unsigned)(bestkey[p] & 0x3FFFFull);
      int p2 = ((int)(pk2 >> 9) == p) ? (int)(pk2 & 511u) : (int)(pk2 >> 9);
      if (p2 == a) {
        partner[a] = p;
        liveF[a] = 0;
      }
    }
    __syncthreads();
    // phase 3: mark rescans + compact live list
    if (tid == 0) nLiveNew = 0;
    __syncthreads();
    for (int idx = tid; idx < nLive; idx += 1024) {
      int a = liveList[idx];
      if (liveF[a]) {
        unsigned pk = 0x3FFFFu - (unsigned)(bestkey[a] & 0x3FFFFull);
        int p = ((int)(pk >> 9) == a) ? (int)(pk & 511u) : (int)(pk >> 9);
        if (!liveF[p]) needs[a] = 1;
        int pos = atomicAdd(&nLiveNew, 1);
        liveTmp[pos] = (short)a;
      }
    }
    __syncthreads();
    int nNew = nLiveNew;
    for (int idx = tid; idx < nNew; idx += 1024) liveList[idx] = liveTmp[idx];
    if (tid == 0) nLiveS = nNew;
    __syncthreads();
  }
  // keep list: kept token = smaller index of each pair, ascending order
  if (wave == 0) {
    int base = 0;
    for (int c = 0; c < 8; ++c) {
      int a = c * 64 + lane;
      bool kept = partner[a] > a;
      unsigned long long m = __ballot(kept);
      int pos = base + (int)__popcll(m & ((1ull << lane) - 1ull));
      if (kept) {
        keepI[b * K_ + pos] = a;
        keepJ[b * K_ + pos] = partner[a];
      }
      base += (int)__popcll(m);
    }
  }
}

// ---------------- Kernel 5: merge x rows -> xm ----------------
__global__ __launch_bounds__(256) void mergex_kernel(const float* __restrict__ x,
                                                     const float* __restrict__ gn,
                                                     const int* __restrict__ keepI,
                                                     const int* __restrict__ keepJ,
                                                     float* __restrict__ out) {
  int row = blockIdx.x;  // 2048 = B*K
  int b = row >> 8;
  int i = keepI[row], j = keepJ[row];
  float wi = gn[(size_t)b * L_ + i], wj = gn[(size_t)b * L_ + j];
  float tot = wi + wj + 1e-8f;
  const float4* xi = (const float4*)(x + ((size_t)b * L_ + i) * D_);
  const float4* xj = (const float4*)(x + ((size_t)b * L_ + j) * D_);
  float4* o = (float4*)(out + (size_t)row * D_);
  int t = threadIdx.x;  // 256 threads x 1 float4 = 1024 floats
  float4 a = xi[t], c = xj[t];
  float4 r;
  r.x = (wi * a.x + wj * c.x) / tot;
  r.y = (wi * a.y + wj * c.y) / tot;
  r.z = (wi * a.z + wj * c.z) / tot;
  r.w = (wi * a.w + wj * c.w) / tot;
  o[t] = r;
}

// ---------------- Kernel 6: merge source rows -> sm ----------------
__global__ __launch_bounds__(256) void merges_kernel(const float* __restrict__ s,
                                                     const int* __restrict__ keepI,
                                                     const int* __restrict__ keepJ,
                                                     float* __restrict__ out) {
  int row = blockIdx.x;  // 2048
  int b = row >> 8;
  int i = keepI[row], j = keepJ[row];
  const float4* si = (const float4*)(s + ((size_t)b * L_ + i) * N_);
  const float4* sj = (const float4*)(s + ((size_t)b * L_ + j) * N_);
  float4* o = (float4*)(out + (size_t)row * N_);
  for (int t = threadIdx.x; t < N_ / 4; t += 256) {
    float4 a = si[t], c = sj[t];
    float4 r;
    r.x = a.x + c.x;
    r.y = a.y + c.y;
    r.z = a.z + c.z;
    r.w = a.w + c.w;
    o[t] = r;
  }
}

extern "C" void kernel_launch(void* const* d_in, const int* in_sizes, int n_in,
                              void* d_out, int out_size, void* d_ws, size_t ws_size,
                              hipStream_t stream) {
  (void)in_sizes; (void)n_in; (void)out_size; (void)ws_size;
  const float* x = (const float*)d_in[0];
  const float* src = (const float*)d_in[1];
  const float* W = (const float*)d_in[2];

  float* ws = (float*)d_ws;
  float* Wt = ws;                                   // 65536
  float* gu = Wt + 65536;                           // 8*512*64 = 262144
  float* gn = gu + (size_t)B_ * L_ * GD_;           // 4096
  float* sim = gn + (size_t)B_ * L_;                // 8*512*512 = 2097152
  int* keepI = (int*)(sim + (size_t)B_ * L_ * L_);  // 2048
  int* keepJ = keepI + B_ * K_;                     // 2048

  float* xm = (float*)d_out;
  float* sm = xm + (size_t)B_ * K_ * D_;

  wt_kernel<<<256, 256, 0, stream>>>(W, Wt);
  gproj_kernel<<<256, 256, 0, stream>>>(x, Wt, gu, gn);
  sim_kernel<<<dim3(16, 16, 8), 256, 0, stream>>>(gu, sim);
  match_kernel<<<B_, 1024, 0, stream>>>(sim, keepI, keepJ);
  mergex_kernel<<<B_ * K_, 256, 0, stream>>>(x, gn, keepI, keepJ, xm);
  merges_kernel<<<B_ * K_, 256, 0, stream>>>(src, keepI, keepJ, sm);
}

// Round 4
// 355.112 us; speedup vs baseline: 1.3316x; 1.3316x over previous
//
#include <hip/hip_runtime.h>

#define B_ 8
#define L_ 512
#define D_ 1024
#define N_ 8192
#define GD_ 64
#define K_ 256

// ---------------- Kernel 1: transpose W (64,1024) -> Wt (1024,64) ----------------
__global__ __launch_bounds__(256) void wt_kernel(const float* __restrict__ W,
                                                 float* __restrict__ Wt) {
  int idx = blockIdx.x * 256 + threadIdx.x;  // 65536 elems
  int d = idx >> 6, g = idx & 63;
  Wt[idx] = W[(size_t)g * D_ + d];
}

// ---------------- Kernel 2: g = x @ W^T, gn = ||g||, gu = g/max(gn,1e-12) --------
__global__ __launch_bounds__(256) void gproj_kernel(const float* __restrict__ x,
                                                    const float* __restrict__ Wt,
                                                    float* __restrict__ gu,
                                                    float* __restrict__ gn) {
  const int KC = 128;
  __shared__ float xs[16][KC];        // 8 KB
  __shared__ float wsT[GD_][KC + 4];  // padded: 33.8 KB
  int blk = blockIdx.x;               // 256 blocks
  int b = blk >> 5;
  int t0 = (blk & 31) * 16;
  int tid = threadIdx.x;
  int dg = tid & 15, tg = tid >> 4;
  const float* xb = x + ((size_t)b * L_ + t0) * D_;
  float ax[4] = {0, 0, 0, 0}, ay[4] = {0, 0, 0, 0};
  float az[4] = {0, 0, 0, 0}, aw[4] = {0, 0, 0, 0};
  for (int kc = 0; kc < D_; kc += KC) {
    for (int f = tid; f < 16 * KC / 4; f += 256) {
      int t = f >> 5, k4 = f & 31;
      *(float4*)&xs[t][k4 * 4] = *(const float4*)(xb + (size_t)t * D_ + kc + k4 * 4);
    }
    for (int f = tid; f < GD_ * KC; f += 256) {
      int kk = f >> 6, d = f & 63;
      wsT[d][kk] = Wt[(size_t)(kc + kk) * GD_ + d];
    }
    __syncthreads();
#pragma unroll 4
    for (int kk = 0; kk < KC; kk += 4) {
      float4 xv = *(const float4*)&xs[tg][kk];
#pragma unroll
      for (int dd = 0; dd < 4; ++dd) {
        float4 wv = *(const float4*)&wsT[dg * 4 + dd][kk];
        ax[dd] += xv.x * wv.x;
        ay[dd] += xv.y * wv.y;
        az[dd] += xv.z * wv.z;
        aw[dd] += xv.w * wv.w;
      }
    }
    __syncthreads();
  }
  float g[4];
  double ss = 0.0;
#pragma unroll
  for (int dd = 0; dd < 4; ++dd) {
    g[dd] = (ax[dd] + ay[dd]) + (az[dd] + aw[dd]);
    ss += (double)g[dd] * (double)g[dd];
  }
#pragma unroll
  for (int off = 1; off < 16; off <<= 1) ss += __shfl_xor(ss, off);
  float gnv = (float)sqrt(ss);
  float dn = fmaxf(gnv, 1e-12f);
  int t = t0 + tg;
  if (dg == 0) gn[(size_t)b * L_ + t] = gnv;
  float* gup = gu + ((size_t)b * L_ + t) * GD_ + dg * 4;
#pragma unroll
  for (int dd = 0; dd < 4; ++dd) gup[dd] = g[dd] / dn;
}

// ---------------- Kernel 3: full 512x512 cosine-sim matrix per batch -------------
// B-tile stored transposed [k][c]; thread owns (r, c4..c4+3): 64 b32 + 64 b128 reads
__global__ __launch_bounds__(256) void sim_kernel(const float* __restrict__ gu,
                                                  float* __restrict__ simo) {
  __shared__ __align__(16) float A[32][65];
  __shared__ __align__(16) float BsT[64][36];
  int b = blockIdx.z;
  int i0 = blockIdx.y * 32, j0 = blockIdx.x * 32;
  const float* gb = gu + (size_t)b * L_ * GD_;
  int tid = threadIdx.x;
  for (int f = tid; f < 32 * GD_; f += 256) {
    int r = f >> 6, k = f & 63;
    A[r][k] = gb[(size_t)(i0 + r) * GD_ + k];
    BsT[k][r] = gb[(size_t)(j0 + r) * GD_ + k];
  }
  __syncthreads();
  int r = tid >> 3, c4 = (tid & 7) * 4;
  double a0 = 0, a1 = 0, a2 = 0, a3 = 0;
#pragma unroll 8
  for (int k = 0; k < GD_; ++k) {
    double a = (double)A[r][k];
    float4 bv = *(const float4*)&BsT[k][c4];
    a0 += a * (double)bv.x;
    a1 += a * (double)bv.y;
    a2 += a * (double)bv.z;
    a3 += a * (double)bv.w;
  }
  float4 o;
  o.x = (float)a0; o.y = (float)a1; o.z = (float)a2; o.w = (float)a3;
  *(float4*)(simo + (size_t)b * L_ * L_ + (size_t)(i0 + r) * L_ + (j0 + c4)) = o;
}

// ---------------- Kernel 4a: per-token sorted top-16 candidate keys --------------
// 1 token per wave; 4096 waves across the GPU. key = (ord(sim)<<18)|(0x3FFFF-(i<<9|j))
__global__ __launch_bounds__(256) void topk_kernel(const float* __restrict__ sim,
                                                   unsigned long long* __restrict__ cand) {
  int wid = blockIdx.x * 4 + (threadIdx.x >> 6);  // 0..4095
  int b = wid >> 9;
  int a = wid & 511;
  int lane = threadIdx.x & 63;
  const float* row = sim + ((size_t)b * L_ + a) * L_;
  int c0 = lane * 8;
  float4 v0 = *(const float4*)(row + c0);
  float4 v1 = *(const float4*)(row + c0 + 4);
  float vv[8] = {v0.x, v0.y, v0.z, v0.w, v1.x, v1.y, v1.z, v1.w};
  unsigned long long k[8];
#pragma unroll
  for (int s = 0; s < 8; ++s) {
    int bb = c0 + s;
    if (bb == a) {
      k[s] = 0;
    } else {
      unsigned u = __float_as_uint(vv[s]);
      u = (u & 0x80000000u) ? ~u : (u | 0x80000000u);
      int i = a < bb ? a : bb, j = a < bb ? bb : a;
      k[s] = ((unsigned long long)u << 18) |
             (unsigned long long)(0x3FFFFu - (((unsigned)i << 9) | (unsigned)j));
    }
  }
  unsigned long long* out = cand + ((size_t)b * L_ + a) * 16;
#pragma unroll
  for (int pass = 0; pass < 16; ++pass) {
    unsigned long long m = k[0];
#pragma unroll
    for (int s = 1; s < 8; ++s) m = k[s] > m ? k[s] : m;
#pragma unroll
    for (int off = 32; off; off >>= 1) {
      unsigned long long o = __shfl_xor(m, off);
      if (o > m) m = o;
    }
#pragma unroll
    for (int s = 0; s < 8; ++s)
      if (k[s] == m) k[s] = 0;
    if (lane == 0) out[pass] = m;
  }
}

// ---------------- Kernel 4b: mutual-best matching with candidate lists -----------
__global__ __launch_bounds__(512) void match_kernel(const float* __restrict__ sim,
                                                    const unsigned long long* __restrict__ cand,
                                                    int* __restrict__ keepI,
                                                    int* __restrict__ keepJ) {
  int b = blockIdx.x;
  const float* S = sim + (size_t)b * L_ * L_;
  const unsigned long long* C = cand + (size_t)b * L_ * 16;
  __shared__ unsigned long long bestkey[L_];
  __shared__ short partner[L_];
  __shared__ short liveList[L_], liveTmp[L_], rescanQ[L_];
  __shared__ unsigned char liveF[L_], needs[L_], head[L_];
  __shared__ int nLiveS, nLiveNew, nQ;
  int tid = threadIdx.x;
  int wave = tid >> 6, lane = tid & 63;
  if (tid < L_) {
    partner[tid] = -1;
    liveF[tid] = 1;
    needs[tid] = 1;
    head[tid] = 0;
    liveList[tid] = (short)tid;
    bestkey[tid] = 0ull;
  }
  if (tid == 0) nLiveS = L_;
  __syncthreads();
  for (int round = 0; round < 300; ++round) {
    int nLive = nLiveS;
    if (nLive == 0) break;
    if (tid == 0) nQ = 0;
    __syncthreads();
    // A: candidate-list pops (thread-per-token)
    for (int idx = tid; idx < nLive; idx += 512) {
      int a = liveList[idx];
      if (needs[a]) {
        int h = head[a];
        unsigned long long bk = 0ull;
        while (h < 16) {
          unsigned long long key = C[a * 16 + h];
          if (key) {
            unsigned pk = 0x3FFFFu - (unsigned)(key & 0x3FFFFull);
            int i = (int)(pk >> 9), j = (int)(pk & 511u);
            int p = (i == a) ? j : i;
            if (liveF[p]) { bk = key; break; }
          }
          ++h;
        }
        head[a] = (unsigned char)h;
        if (bk) {
          bestkey[a] = bk;
          needs[a] = 0;
        } else {
          int q = atomicAdd(&nQ, 1);
          rescanQ[q] = (short)a;
        }
      }
    }
    __syncthreads();
    // A2: full rescans for exhausted lists (wave-per-token, rare)
    int nq = nQ;
    for (int q = wave; q < nq; q += 8) {
      int a = rescanQ[q];
      unsigned long long mk = 0ull;
      for (int kk = lane; kk < nLive; kk += 64) {
        int bb = liveList[kk];
        if (bb != a) {
          float sv = S[(size_t)a * L_ + bb];
          unsigned u = __float_as_uint(sv);
          u = (u & 0x80000000u) ? ~u : (u | 0x80000000u);
          int i = a < bb ? a : bb, j = a < bb ? bb : a;
          unsigned long long key =
              ((unsigned long long)u << 18) |
              (unsigned long long)(0x3FFFFu - (((unsigned)i << 9) | (unsigned)j));
          if (key > mk) mk = key;
        }
      }
#pragma unroll
      for (int off = 32; off; off >>= 1) {
        unsigned long long o = __shfl_xor(mk, off);
        if (o > mk) mk = o;
      }
      if (lane == 0) {
        bestkey[a] = mk;
        needs[a] = 0;
      }
    }
    __syncthreads();
    // B: mutual-best match
    for (int idx = tid; idx < nLive; idx += 512) {
      int a = liveList[idx];
      unsigned pk = 0x3FFFFu - (unsigned)(bestkey[a] & 0x3FFFFull);
      int i = (int)(pk >> 9), j = (int)(pk & 511u);
      int p = (i == a) ? j : i;
      unsigned pk2 = 0x3FFFFu - (unsigned)(bestkey[p] & 0x3FFFFull);
      int i2 = (int)(pk2 >> 9), j2 = (int)(pk2 & 511u);
      int p2 = (i2 == p) ? j2 : i2;
      if (p2 == a) {
        partner[a] = (short)p;
        liveF[a] = 0;
      }
    }
    __syncthreads();
    // C: compact live list + mark tokens whose best died
    if (tid == 0) nLiveNew = 0;
    __syncthreads();
    for (int idx = tid; idx < nLive; idx += 512) {
      int a = liveList[idx];
      if (liveF[a]) {
        unsigned pk = 0x3FFFFu - (unsigned)(bestkey[a] & 0x3FFFFull);
        int i = (int)(pk >> 9), j = (int)(pk & 511u);
        int p = (i == a) ? j : i;
        if (!liveF[p]) needs[a] = 1;
        int pos = atomicAdd(&nLiveNew, 1);
        liveTmp[pos] = (short)a;
      }
    }
    __syncthreads();
    int nNew = nLiveNew;
    for (int idx = tid; idx < nNew; idx += 512) liveList[idx] = liveTmp[idx];
    if (tid == 0) nLiveS = nNew;
    __syncthreads();
  }
  // keep list: kept token = smaller index of each pair, ascending order
  if (wave == 0) {
    int base = 0;
    for (int c = 0; c < 8; ++c) {
      int a = c * 64 + lane;
      bool kept = partner[a] > a;
      unsigned long long m = __ballot(kept);
      int pos = base + (int)__popcll(m & ((1ull << lane) - 1ull));
      if (kept) {
        keepI[b * K_ + pos] = a;
        keepJ[b * K_ + pos] = partner[a];
      }
      base += (int)__popcll(m);
    }
  }
}

// ---------------- Kernel 5: merge x rows -> xm ----------------
__global__ __launch_bounds__(256) void mergex_kernel(const float* __restrict__ x,
                                                     const float* __restrict__ gn,
                                                     const int* __restrict__ keepI,
                                                     const int* __restrict__ keepJ,
                                                     float* __restrict__ out) {
  int row = blockIdx.x;  // 2048 = B*K
  int b = row >> 8;
  int i = keepI[row], j = keepJ[row];
  float wi = gn[(size_t)b * L_ + i], wj = gn[(size_t)b * L_ + j];
  float tot = wi + wj + 1e-8f;
  const float4* xi = (const float4*)(x + ((size_t)b * L_ + i) * D_);
  const float4* xj = (const float4*)(x + ((size_t)b * L_ + j) * D_);
  float4* o = (float4*)(out + (size_t)row * D_);
  int t = threadIdx.x;
  float4 a = xi[t], c = xj[t];
  float4 r;
  r.x = (wi * a.x + wj * c.x) / tot;
  r.y = (wi * a.y + wj * c.y) / tot;
  r.z = (wi * a.z + wj * c.z) / tot;
  r.w = (wi * a.w + wj * c.w) / tot;
  o[t] = r;
}

// ---------------- Kernel 6: merge source rows -> sm ----------------
__global__ __launch_bounds__(256) void merges_kernel(const float* __restrict__ s,
                                                     const int* __restrict__ keepI,
                                                     const int* __restrict__ keepJ,
                                                     float* __restrict__ out) {
  int row = blockIdx.x;  // 2048
  int b = row >> 8;
  int i = keepI[row], j = keepJ[row];
  const float4* si = (const float4*)(s + ((size_t)b * L_ + i) * N_);
  const float4* sj = (const float4*)(s + ((size_t)b * L_ + j) * N_);
  float4* o = (float4*)(out + (size_t)row * N_);
  for (int t = threadIdx.x; t < N_ / 4; t += 256) {
    float4 a = si[t], c = sj[t];
    float4 r;
    r.x = a.x + c.x;
    r.y = a.y + c.y;
    r.z = a.z + c.z;
    r.w = a.w + c.w;
    o[t] = r;
  }
}

extern "C" void kernel_launch(void* const* d_in, const int* in_sizes, int n_in,
                              void* d_out, int out_size, void* d_ws, size_t ws_size,
                              hipStream_t stream) {
  (void)in_sizes; (void)n_in; (void)out_size; (void)ws_size;
  const float* x = (const float*)d_in[0];
  const float* src = (const float*)d_in[1];
  const float* W = (const float*)d_in[2];

  float* ws = (float*)d_ws;
  float* Wt = ws;                                   // 65536
  float* gu = Wt + 65536;                           // 262144
  float* gn = gu + (size_t)B_ * L_ * GD_;           // 4096
  float* sim = gn + (size_t)B_ * L_;                // 2097152
  int* keepI = (int*)(sim + (size_t)B_ * L_ * L_);  // 2048
  int* keepJ = keepI + B_ * K_;                     // 2048
  unsigned long long* cand = (unsigned long long*)(keepJ + B_ * K_);  // 8*512*16 u64

  float* xm = (float*)d_out;
  float* sm = xm + (size_t)B_ * K_ * D_;

  wt_kernel<<<256, 256, 0, stream>>>(W, Wt);
  gproj_kernel<<<256, 256, 0, stream>>>(x, Wt, gu, gn);
  sim_kernel<<<dim3(16, 16, 8), 256, 0, stream>>>(gu, sim);
  topk_kernel<<<1024, 256, 0, stream>>>(sim, cand);
  match_kernel<<<B_, 512, 0, stream>>>(sim, cand, keepI, keepJ);
  mergex_kernel<<<B_ * K_, 256, 0, stream>>>(x, gn, keepI, keepJ, xm);
  merges_kernel<<<B_ * K_, 256, 0, stream>>>(src, keepI, keepJ, sm);
}